// Round 1
// baseline (406.635 us; speedup 1.0000x reference)
//
#include <hip/hip_runtime.h>

typedef __attribute__((ext_vector_type(8))) short bf16x8;
typedef __attribute__((ext_vector_type(4))) float f32x4;

#define K_DIM 4096
#define N_DIM 4096
#define BM 128
#define BN 128
#define BK 32

// ---------- helpers ----------

__device__ __forceinline__ unsigned short f2bf(float f) {
  union { float f; unsigned u; } c; c.f = f;
  unsigned u = c.u;
  // round-to-nearest-even f32 -> bf16
  return (unsigned short)((u + 0x7fffu + ((u >> 16) & 1u)) >> 16);
}

__device__ __forceinline__ void gload16(const unsigned short* g, unsigned short* l) {
  // async global -> LDS, 16 bytes per lane (lds dest = wave-uniform base + lane*16)
  __builtin_amdgcn_global_load_lds(
      (const __attribute__((address_space(1))) void*)g,
      (__attribute__((address_space(3))) void*)l,
      16, 0, 0);
}

// ---------- prep: 2:4 prune x (fp32 semantics identical to jax top_k) + cast bf16 ----------

__global__ void __launch_bounds__(256) prune_cast_x(const float* __restrict__ x,
                                                    unsigned short* __restrict__ xb,
                                                    long ngroups) {
  long stride = (long)gridDim.x * blockDim.x;
  for (long g = (long)blockIdx.x * blockDim.x + threadIdx.x; g < ngroups; g += stride) {
    float4 v = reinterpret_cast<const float4*>(x)[g];
    float vv[4] = {v.x, v.y, v.z, v.w};
    float av[4] = {fabsf(v.x), fabsf(v.y), fabsf(v.z), fabsf(v.w)};
    unsigned short o[4];
#pragma unroll
    for (int i = 0; i < 4; ++i) {
      int beats = 0;
#pragma unroll
      for (int j = 0; j < 4; ++j) {
        if (j == i) continue;
        // j beats i if larger |x|, or equal |x| with lower index (top_k tie rule)
        beats += (av[j] > av[i] || (av[j] == av[i] && j < i)) ? 1 : 0;
      }
      o[i] = f2bf(beats < 2 ? vv[i] : 0.0f);
    }
    ushort4 pk; pk.x = o[0]; pk.y = o[1]; pk.z = o[2]; pk.w = o[3];
    reinterpret_cast<ushort4*>(xb)[g] = pk;
  }
}

__global__ void __launch_bounds__(256) cast_w(const float* __restrict__ w,
                                              unsigned short* __restrict__ wb,
                                              long ngroups) {
  long stride = (long)gridDim.x * blockDim.x;
  for (long g = (long)blockIdx.x * blockDim.x + threadIdx.x; g < ngroups; g += stride) {
    float4 v = reinterpret_cast<const float4*>(w)[g];
    ushort4 pk;
    pk.x = f2bf(v.x); pk.y = f2bf(v.y); pk.z = f2bf(v.z); pk.w = f2bf(v.w);
    reinterpret_cast<ushort4*>(wb)[g] = pk;
  }
}

// ---------- GEMM: C[m][n] = sum_k A[m][k] * B[n][k], A/B bf16 K-major, C fp32 ----------
// m97 structure: 128x128 tile, BK=32, 4 waves (2x2), 16x16x32 MFMA, global_load_lds.

__global__ void __launch_bounds__(256, 2) gemm_bt(const unsigned short* __restrict__ A,
                                                  const unsigned short* __restrict__ B,
                                                  float* __restrict__ C,
                                                  int Mdim) {
  __shared__ unsigned short As[BM * BK];
  __shared__ unsigned short Bs[BN * BK];

  const int nbn = N_DIM / BN;  // 32
  const int nwg = gridDim.x;
  const int cpx = nwg >> 3;    // grid % 8 == 0 -> bijective XCD swizzle
  int bid = blockIdx.x;
  int swz = (bid & 7) * cpx + (bid >> 3);
  int bm = swz / nbn;
  int bn = swz % nbn;

  const int tid = threadIdx.x;
  const int lane = tid & 63;
  const int wid = tid >> 6;
  const int wr = wid >> 1;   // 0..1
  const int wc = wid & 1;    // 0..1

  const int r = lane & 15;   // fragment row/col within 16
  const int kq = lane >> 4;  // k-quad 0..3

  f32x4 acc[4][4] = {};

  const size_t aBase = (size_t)bm * BM * K_DIM;
  const size_t bBase = (size_t)bn * BN * K_DIM;

  const int c0 = tid;        // staging chunk ids (512 x 16B per tile)
  const int c1 = tid + 256;

  for (int k0 = 0; k0 < K_DIM; k0 += BK) {
    // stage A and B tiles: chunk c -> row c>>2, k-offset (c&3)*8
    gload16(A + aBase + (size_t)(c0 >> 2) * K_DIM + k0 + (c0 & 3) * 8, &As[c0 * 8]);
    gload16(A + aBase + (size_t)(c1 >> 2) * K_DIM + k0 + (c1 & 3) * 8, &As[c1 * 8]);
    gload16(B + bBase + (size_t)(c0 >> 2) * K_DIM + k0 + (c0 & 3) * 8, &Bs[c0 * 8]);
    gload16(B + bBase + (size_t)(c1 >> 2) * K_DIM + k0 + (c1 & 3) * 8, &Bs[c1 * 8]);
    __syncthreads();  // vmcnt(0) drain + barrier: tiles ready

    bf16x8 af[4], bfr[4];
#pragma unroll
    for (int m = 0; m < 4; ++m)
      af[m] = *reinterpret_cast<const bf16x8*>(&As[(wr * 64 + m * 16 + r) * BK + kq * 8]);
#pragma unroll
    for (int n = 0; n < 4; ++n)
      bfr[n] = *reinterpret_cast<const bf16x8*>(&Bs[(wc * 64 + n * 16 + r) * BK + kq * 8]);

#pragma unroll
    for (int m = 0; m < 4; ++m)
#pragma unroll
      for (int n = 0; n < 4; ++n)
        acc[m][n] = __builtin_amdgcn_mfma_f32_16x16x32_bf16(af[m], bfr[n], acc[m][n], 0, 0, 0);

    __syncthreads();  // all reads done before next overwrite
  }

  // epilogue: C/D layout col=lane&15, row=(lane>>4)*4+reg
  const int rowBase = bm * BM + wr * 64 + kq * 4;
  const int colBase = bn * BN + wc * 64 + r;
#pragma unroll
  for (int m = 0; m < 4; ++m)
#pragma unroll
    for (int n = 0; n < 4; ++n) {
      const int col = colBase + n * 16;
#pragma unroll
      for (int i = 0; i < 4; ++i)
        C[(size_t)(rowBase + m * 16 + i) * N_DIM + col] = acc[m][n][i];
    }
}

// ---------- launch ----------

extern "C" void kernel_launch(void* const* d_in, const int* in_sizes, int n_in,
                              void* d_out, int out_size, void* d_ws, size_t ws_size,
                              hipStream_t stream) {
  const float* x = (const float*)d_in[0];
  const float* w = (const float*)d_in[1];
  float* out = (float*)d_out;

  const int Mdim = in_sizes[0] / K_DIM;          // 8192
  const long xGroups = (long)in_sizes[0] / 4;    // 8.39M groups of 4
  const long wGroups = (long)in_sizes[1] / 4;

  unsigned short* xb = (unsigned short*)d_ws;                  // M*K bf16 (64 MB)
  unsigned short* wb = xb + (size_t)Mdim * K_DIM;              // N*K bf16 (32 MB)

  prune_cast_x<<<2048, 256, 0, stream>>>(x, xb, xGroups);
  cast_w<<<1024, 256, 0, stream>>>(w, wb, wGroups);

  const int grid = (Mdim / BM) * (N_DIM / BN);   // 64 * 32 = 2048
  gemm_bt<<<grid, 256, 0, stream>>>(xb, wb, out, Mdim);
}

// Round 2
// 291.879 us; speedup vs baseline: 1.3932x; 1.3932x over previous
//
#include <hip/hip_runtime.h>

typedef __attribute__((ext_vector_type(8))) short bf16x8;
typedef __attribute__((ext_vector_type(4))) float f32x4;

#define K_DIM 4096
#define N_DIM 4096
#define BM 256
#define BN 256
#define BK 64
#define NT (K_DIM / BK)   // 64 K-tiles
#define HALF (128 * BK)   // ushorts per half-tile (8192)
#define BOFF (BM * BK)    // B region offset within a buffer (16384 ushorts)

// ---------- helpers ----------

__device__ __forceinline__ unsigned short f2bf(float f) {
  union { float f; unsigned u; } c; c.f = f;
  unsigned u = c.u;
  return (unsigned short)((u + 0x7fffu + ((u >> 16) & 1u)) >> 16);  // RNE f32->bf16
}

__device__ __forceinline__ void gload16(const unsigned short* g, unsigned short* l) {
  __builtin_amdgcn_global_load_lds(
      (const __attribute__((address_space(1))) void*)g,
      (__attribute__((address_space(3))) void*)l,
      16, 0, 0);
}

// swizzled LDS fragment read: logical [row][64] bf16, byte ^= (row&7)<<4
__device__ __forceinline__ bf16x8 ldfrag_(const unsigned short* p, int row, int k8) {
  int o = row * BK + k8 * 8;      // ushort offset
  o ^= (row & 7) << 3;            // = byte ^ (row&7)<<4
  return *reinterpret_cast<const bf16x8*>(p + o);
}

// ---------- prep: 2:4 prune x (exact top_k tie rule) + cast bf16 ----------

__global__ void __launch_bounds__(256) prune_cast_x(const float* __restrict__ x,
                                                    unsigned short* __restrict__ xb,
                                                    long ngroups) {
  long stride = (long)gridDim.x * blockDim.x;
  for (long g = (long)blockIdx.x * blockDim.x + threadIdx.x; g < ngroups; g += stride) {
    float4 v = reinterpret_cast<const float4*>(x)[g];
    float vv[4] = {v.x, v.y, v.z, v.w};
    float av[4] = {fabsf(v.x), fabsf(v.y), fabsf(v.z), fabsf(v.w)};
    unsigned short o[4];
#pragma unroll
    for (int i = 0; i < 4; ++i) {
      int beats = 0;
#pragma unroll
      for (int j = 0; j < 4; ++j) {
        if (j == i) continue;
        beats += (av[j] > av[i] || (av[j] == av[i] && j < i)) ? 1 : 0;
      }
      o[i] = f2bf(beats < 2 ? vv[i] : 0.0f);
    }
    ushort4 pk; pk.x = o[0]; pk.y = o[1]; pk.z = o[2]; pk.w = o[3];
    reinterpret_cast<ushort4*>(xb)[g] = pk;
  }
}

__global__ void __launch_bounds__(256) cast_w(const float* __restrict__ w,
                                              unsigned short* __restrict__ wb,
                                              long ngroups) {
  long stride = (long)gridDim.x * blockDim.x;
  for (long g = (long)blockIdx.x * blockDim.x + threadIdx.x; g < ngroups; g += stride) {
    float4 v = reinterpret_cast<const float4*>(w)[g];
    ushort4 pk;
    pk.x = f2bf(v.x); pk.y = f2bf(v.y); pk.z = f2bf(v.z); pk.w = f2bf(v.w);
    reinterpret_cast<ushort4*>(wb)[g] = pk;
  }
}

// ---------- 256x256 8-phase GEMM: C[m][n] = sum_k A[m][k]*B[n][k] ----------
// 8 waves (2Mx4N), BK=64, dbuf LDS 128KiB, counted vmcnt, XOR-swizzled LDS.

// per-phase macros (all indices compile-time so acc/a/b stay in registers)
#define LD_A(LP, MH)                                                        \
  _Pragma("unroll") for (int m_ = 0; m_ < 4; ++m_)                          \
  _Pragma("unroll") for (int ks_ = 0; ks_ < 2; ++ks_)                       \
    a[m_][ks_] = ldfrag_((LP), wrow0 + (MH)*64 + m_*16 + r, ks_*4 + kq);

#define LD_B(LP, NH, BV)                                                    \
  _Pragma("unroll") for (int n_ = 0; n_ < 2; ++n_)                          \
  _Pragma("unroll") for (int ks_ = 0; ks_ < 2; ++ks_)                       \
    BV[n_][ks_] = ldfrag_((LP) + BOFF, wcol0 + (NH)*32 + n_*16 + r, ks_*4 + kq);

#define QUAD(MH, NH, BV)                                                    \
  _Pragma("unroll") for (int m_ = 0; m_ < 4; ++m_)                          \
  _Pragma("unroll") for (int n_ = 0; n_ < 2; ++n_)                          \
  _Pragma("unroll") for (int ks_ = 0; ks_ < 2; ++ks_)                       \
    acc[(MH)*4 + m_][(NH)*2 + n_] = __builtin_amdgcn_mfma_f32_16x16x32_bf16( \
        a[m_][ks_], BV[n_][ks_], acc[(MH)*4 + m_][(NH)*2 + n_], 0, 0, 0);

#define STG(G, O0, O1, LP, KK)                                              \
  do { gload16((G) + (O0) + (KK), (LP) + l0);                               \
       gload16((G) + (O1) + (KK), (LP) + l1); } while (0)

__global__ void __launch_bounds__(512, 2) gemm256(const unsigned short* __restrict__ A,
                                                  const unsigned short* __restrict__ B,
                                                  float* __restrict__ C, int Mdim) {
  __shared__ unsigned short lds[2][2 * BM * BK];  // [buf][ A(16384) | B(16384) ]

  const int nbn = N_DIM / BN;                 // 16
  const int cpx = gridDim.x >> 3;             // grid % 8 == 0 (bijective XCD swizzle)
  const int bid = blockIdx.x;
  const int swz = (bid & 7) * cpx + (bid >> 3);
  const int bm = swz / nbn, bn = swz % nbn;

  const int tid = threadIdx.x;
  const int lane = tid & 63;
  const int wid = tid >> 6;
  const int wr = wid >> 2;                    // 0..1: M half
  const int wc = wid & 3;                     // 0..3: N quarter
  const int r = lane & 15;
  const int kq = lane >> 4;
  const int wrow0 = wr * 128;
  const int wcol0 = wc * 64;

  // staging: 1024 chunks of 16B per half-tile; thread covers chunks tid, tid+512.
  // linear LDS dest; inverse-swizzled global source (involution: c ^= (c>>3)&7)
  const int c0 = tid, c1 = tid + 512;
  const int s0 = c0 ^ ((c0 >> 3) & 7);
  const int s1 = c1 ^ ((c1 >> 3) & 7);
  const int l0 = c0 * 8, l1 = c1 * 8;         // lds ushort offsets within half
  const size_t aRow = (size_t)bm * BM, bRow = (size_t)bn * BN;
  const size_t gA00 = (aRow +       (s0 >> 3)) * K_DIM + (s0 & 7) * 8;
  const size_t gA01 = (aRow +       (s1 >> 3)) * K_DIM + (s1 & 7) * 8;
  const size_t gA10 = (aRow + 128 + (s0 >> 3)) * K_DIM + (s0 & 7) * 8;
  const size_t gA11 = (aRow + 128 + (s1 >> 3)) * K_DIM + (s1 & 7) * 8;
  const size_t gB00 = (bRow +       (s0 >> 3)) * K_DIM + (s0 & 7) * 8;
  const size_t gB01 = (bRow +       (s1 >> 3)) * K_DIM + (s1 & 7) * 8;
  const size_t gB10 = (bRow + 128 + (s0 >> 3)) * K_DIM + (s0 & 7) * 8;
  const size_t gB11 = (bRow + 128 + (s1 >> 3)) * K_DIM + (s1 & 7) * 8;

  bf16x8 a[4][2], b0[2][2], b1[2][2];
  f32x4 acc[8][4] = {};

  // prologue: tile0 (all 4 halves) + tile1 A-h0; wait all but last half
  STG(A, gA00, gA01, &lds[0][0], 0);
  STG(A, gA10, gA11, &lds[0][HALF], 0);
  STG(B, gB00, gB01, &lds[0][BOFF], 0);
  STG(B, gB10, gB11, &lds[0][BOFF + HALF], 0);
  STG(A, gA00, gA01, &lds[1][0], BK);
  asm volatile("s_waitcnt vmcnt(2)" ::: "memory");
  __builtin_amdgcn_s_barrier();

  for (int t = 0; t < NT; ++t) {
    unsigned short* Lc = lds[t & 1];
    unsigned short* Ln = lds[(t & 1) ^ 1];
    const int k1 = ((t + 1) & (NT - 1)) * BK;  // wraps at tail: redundant, harmless
    const int k2 = ((t + 2) & (NT - 1)) * BK;

    // P1: A[mh0] + B[nh0] reads; stage A-h1(t+1); quadrant (0,0)
    LD_A(Lc, 0);
    LD_B(Lc, 0, b0);
    STG(A, gA10, gA11, Ln + HALF, k1);
    __builtin_amdgcn_s_barrier();
    asm volatile("s_waitcnt lgkmcnt(0)" ::: "memory");
    __builtin_amdgcn_s_setprio(1);
    QUAD(0, 0, b0);
    __builtin_amdgcn_s_setprio(0);
    __builtin_amdgcn_s_barrier();

    // P2: B[nh1] reads; stage B-h0(t+1); quadrant (0,1)
    LD_B(Lc, 1, b1);
    STG(B, gB00, gB01, Ln + BOFF, k1);
    __builtin_amdgcn_s_barrier();
    asm volatile("s_waitcnt lgkmcnt(0)" ::: "memory");
    __builtin_amdgcn_s_setprio(1);
    QUAD(0, 1, b1);
    __builtin_amdgcn_s_setprio(0);
    __builtin_amdgcn_s_barrier();

    // P3: A[mh1] reads; stage B-h1(t+1); quadrant (1,1)
    LD_A(Lc, 1);
    STG(B, gB10, gB11, Ln + BOFF + HALF, k1);
    __builtin_amdgcn_s_barrier();
    asm volatile("s_waitcnt lgkmcnt(0)" ::: "memory");
    __builtin_amdgcn_s_setprio(1);
    QUAD(1, 1, b1);
    __builtin_amdgcn_s_setprio(0);
    __builtin_amdgcn_s_barrier();

    // P4: B[nh0] reads; stage A-h0(t+2) into current buffer (A reads done at P3);
    //     counted vmcnt(2): all 4 halves of t+1 resident, t+2's A-h0 stays in flight
    LD_B(Lc, 0, b0);
    STG(A, gA00, gA01, Lc, k2);
    __builtin_amdgcn_s_barrier();
    asm volatile("s_waitcnt lgkmcnt(0)" ::: "memory");
    __builtin_amdgcn_s_setprio(1);
    QUAD(1, 0, b0);
    __builtin_amdgcn_s_setprio(0);
    asm volatile("s_waitcnt vmcnt(2)" ::: "memory");
    __builtin_amdgcn_s_barrier();
  }

  // epilogue: C/D layout col=lane&15, row=(lane>>4)*4+i
  const int rb = bm * BM + wrow0 + kq * 4;
  const int cb = bn * BN + wcol0 + r;
#pragma unroll
  for (int m = 0; m < 8; ++m)
#pragma unroll
    for (int n = 0; n < 4; ++n) {
      const int col = cb + n * 16;
#pragma unroll
      for (int i = 0; i < 4; ++i)
        C[(size_t)(rb + m * 16 + i) * N_DIM + col] = acc[m][n][i];
    }
}

// ---------- launch ----------

extern "C" void kernel_launch(void* const* d_in, const int* in_sizes, int n_in,
                              void* d_out, int out_size, void* d_ws, size_t ws_size,
                              hipStream_t stream) {
  const float* x = (const float*)d_in[0];
  const float* w = (const float*)d_in[1];
  float* out = (float*)d_out;

  const int Mdim = in_sizes[0] / K_DIM;        // 8192
  const long xGroups = (long)in_sizes[0] / 4;
  const long wGroups = (long)in_sizes[1] / 4;

  unsigned short* xb = (unsigned short*)d_ws;              // M*K bf16 (64 MB)
  unsigned short* wb = xb + (size_t)Mdim * K_DIM;          // N*K bf16 (32 MB)

  prune_cast_x<<<2048, 256, 0, stream>>>(x, xb, xGroups);
  cast_w<<<1024, 256, 0, stream>>>(w, wb, wGroups);

  const int grid = (Mdim / BM) * (N_DIM / BN);             // 32 * 16 = 512
  gemm256<<<grid, 512, 0, stream>>>(xb, wb, out, Mdim);
}